// Round 7
// baseline (569.743 us; speedup 1.0000x reference)
//
#include <hip/hip_runtime.h>
#include <math.h>
#include <stdint.h>

#define B_ 8
#define T_ 128
#define U1_ 33
#define D_ 512
#define V_ 4096
#define M_ (B_*T_*U1_)   /* 33792 */

#define BLANK_ 0
#define PAD_ 1

#define TM 128
#define TN 128
#define BKB 128          /* K per MFMA step (fp8 bytes) */
#define NK (D_/BKB)      /* 4 */
#define NBX (M_/TM)      /* 264 */
#define NBY (V_/TN)      /* 32 */
#define NB  (NBX*NBY)    /* 8448 */

/* E8M0 block scales: A x1 (bias 127); B x2^-6 (121) undoes the x64 pre-scale */
#define SCALE_A 0x7F7F7F7Fu
#define SCALE_B 0x79797979u

typedef __attribute__((ext_vector_type(4))) float fvec4;
typedef __attribute__((ext_vector_type(8))) int   i8v;    // 32 fp8 = 8 VGPRs
typedef __attribute__((ext_vector_type(4))) int   i4v;

__device__ __forceinline__ void load_lds16(const uint8_t* g, uint8_t* l) {
    __builtin_amdgcn_global_load_lds(
        (const __attribute__((address_space(1))) unsigned int*)g,
        (__attribute__((address_space(3))) unsigned int*)l, 16, 0, 0);
}

__device__ __forceinline__ unsigned pack4_fp8(fvec4 v) {
    int r = __builtin_amdgcn_cvt_pk_fp8_f32(v.x, v.y, 0, false);
    r = __builtin_amdgcn_cvt_pk_fp8_f32(v.z, v.w, r, true);
    return (unsigned)r;
}

// ---------------------------------------------------------------------------
// Kernel 0: convert x,w fp32 -> fp8 (w pre-scaled x64); zero pe/pz/out/counter
// ---------------------------------------------------------------------------
__global__ void prep_kernel(const float* __restrict__ x, const float* __restrict__ w,
                            uint8_t* __restrict__ xf8, uint8_t* __restrict__ wf8,
                            float* __restrict__ pe, float* __restrict__ pz,
                            unsigned* __restrict__ counter, float* __restrict__ out)
{
    int i = blockIdx.x * 256 + threadIdx.x;
    int stride = gridDim.x * 256;
    if (i == 0) { out[0] = 0.0f; counter[0] = 0u; }
    for (int j = i; j < M_; j += stride) { pe[j] = 0.0f; pz[j] = 0.0f; }
    const int nx = (M_ * D_) / 16;   // 1081344 groups of 16 elems
    const int nw = (V_ * D_) / 16;   // 131072
    for (int j = i; j < nx; j += stride) {
        const fvec4* p = (const fvec4*)x + (size_t)j * 4;
        uint4 o = { pack4_fp8(p[0]), pack4_fp8(p[1]), pack4_fp8(p[2]), pack4_fp8(p[3]) };
        ((uint4*)xf8)[j] = o;
    }
    for (int j = i; j < nw; j += stride) {
        const fvec4* p = (const fvec4*)w + (size_t)j * 4;
        fvec4 v0 = p[0]*64.0f, v1 = p[1]*64.0f, v2 = p[2]*64.0f, v3 = p[3]*64.0f;
        uint4 o = { pack4_fp8(v0), pack4_fp8(v1), pack4_fp8(v2), pack4_fp8(v3) };
        ((uint4*)wf8)[j] = o;
    }
}

// ---------------------------------------------------------------------------
// Kernel 1: MX-fp8 GEMM (R3 structure, 512-thread blocks for 2x occupancy)
// + epilogue (sum-exp/sum-z via global atomics, blank/target logit extract)
// + fan-in tail: last block runs lp precompute, CE, and 8-wave RNN-T DP.
// grid (264, 32), block 512 = 4x2 waves, wave tile 32 rows x 64 cols.
// ---------------------------------------------------------------------------
__global__ __launch_bounds__(512, 2)
void gemm_fused(const uint8_t* __restrict__ xf8, const uint8_t* __restrict__ wf8,
                const float* __restrict__ bias, const int* __restrict__ targets,
                const int* __restrict__ src_lengths, const int* __restrict__ tgt_lengths,
                float* __restrict__ pe, float* __restrict__ pz,
                float* __restrict__ blank_z, float* __restrict__ emit_z,
                float* __restrict__ blp_g, float* __restrict__ elp_g,
                unsigned* __restrict__ counter, float* __restrict__ out)
{
    __shared__ __align__(16) uint8_t As[2][TM * BKB];   // 16 KB x2
    __shared__ __align__(16) uint8_t Bs[2][TN * BKB];   // 16 KB x2
    __shared__ float ps[TM], pzs[TM];
    __shared__ int tgt_s[TM];
    __shared__ int tail_flag;

    const int tid  = threadIdx.x;
    const int lane = tid & 63;
    const int wid  = tid >> 6;                 // 0..7
    const int m0   = blockIdx.x * TM;
    const int n0   = blockIdx.y * TN;

    // staging: 8 waves x (8 rows/issue) x 2 issues = 128 rows per matrix.
    // lane -> row srow+(j*64), 16B chunk (lane&7) XOR-swizzled by row&7.
    const int srow = wid * 8 + (lane >> 3);
    const int schk = (lane & 7) ^ ((lane >> 3) & 7);
    const uint8_t* agp = xf8 + (size_t)(m0 + srow) * D_ + schk * 16;
    const uint8_t* bgp = wf8 + (size_t)(n0 + srow) * D_ + schk * 16;
    const int lbase = (wid * 8) * BKB;

    auto stage = [&](int buf, int ks) {
        const uint8_t* ag = agp + ks * BKB;
        const uint8_t* bg = bgp + ks * BKB;
#pragma unroll
        for (int j = 0; j < 2; j++) {
            load_lds16(ag + j * 64 * D_, &As[buf][lbase + j * 64 * BKB]);
            load_lds16(bg + j * 64 * D_, &Bs[buf][lbase + j * 64 * BKB]);
        }
    };

    if (tid < TM) {
        int row = m0 + tid, u = row % U1_, b = row / (T_ * U1_);
        tgt_s[tid] = (u < U1_ - 1) ? targets[b * (U1_ - 1) + u] : -1;
        ps[tid] = 0.0f; pzs[tid] = 0.0f;
    }

    fvec4 acc[2][4];
#pragma unroll
    for (int i = 0; i < 2; i++)
#pragma unroll
        for (int j = 0; j < 4; j++) acc[i][j] = (fvec4)0.0f;

    const int wrow = (wid >> 1) * 32;          // 0,32,64,96 (x2 col-halves)
    const int wcol = (wid & 1) * 64;
    const int m15  = lane & 15;
    const int quad = lane >> 4;

    stage(0, 0);
    __syncthreads();

    const int e   = m15 & 7;
    const int c0b = (((quad << 1) ^ e) << 4);

    for (int ks = 0; ks < NK; ks++) {
        const int cur = ks & 1;
        if (ks + 1 < NK) stage(cur ^ 1, ks + 1);

        i8v fa[2], fb[4];
#pragma unroll
        for (int mi = 0; mi < 2; mi++) {
            const int base = (wrow + mi * 16 + m15) * BKB;
            union { i4v h[2]; i8v w; } u;
            u.h[0] = *(const i4v*)&As[cur][base + c0b];
            u.h[1] = *(const i4v*)&As[cur][base + (c0b ^ 16)];
            fa[mi] = u.w;
        }
#pragma unroll
        for (int ni = 0; ni < 4; ni++) {
            const int base = (wcol + ni * 16 + m15) * BKB;
            union { i4v h[2]; i8v w; } u;
            u.h[0] = *(const i4v*)&Bs[cur][base + c0b];
            u.h[1] = *(const i4v*)&Bs[cur][base + (c0b ^ 16)];
            fb[ni] = u.w;
        }
#pragma unroll
        for (int mi = 0; mi < 2; mi++)
#pragma unroll
            for (int ni = 0; ni < 4; ni++)
                acc[mi][ni] = __builtin_amdgcn_mfma_scale_f32_16x16x128_f8f6f4(
                                  fa[mi], fb[ni], acc[mi][ni],
                                  0, 0, 0, SCALE_A, 0, SCALE_B);
        __syncthreads();
    }

    // ---- epilogue ----
    float bv[4];
#pragma unroll
    for (int ni = 0; ni < 4; ni++) bv[ni] = bias[n0 + wcol + ni * 16 + m15];

    const bool blank_lane = (blockIdx.y == 0) && (wcol == 0) && (m15 == 0);

#pragma unroll
    for (int mi = 0; mi < 2; mi++) {
#pragma unroll
        for (int r = 0; r < 4; r++) {
            const int irow = wrow + mi * 16 + quad * 4 + r;
            const int trg = tgt_s[irow];
            float se = 0.0f, sz = 0.0f;
#pragma unroll
            for (int ni = 0; ni < 4; ni++) {
                float z = acc[mi][ni][r] + bv[ni];
                se += __expf(z);
                sz += z;
                if (trg == n0 + wcol + ni * 16 + m15) emit_z[m0 + irow] = z;
            }
            if (blank_lane) blank_z[m0 + irow] = acc[mi][0][r] + bv[0];
            se += __shfl_xor(se, 1, 64); sz += __shfl_xor(sz, 1, 64);
            se += __shfl_xor(se, 2, 64); sz += __shfl_xor(sz, 2, 64);
            se += __shfl_xor(se, 4, 64); sz += __shfl_xor(sz, 4, 64);
            se += __shfl_xor(se, 8, 64); sz += __shfl_xor(sz, 8, 64);
            if (m15 == 0) { atomicAdd(&ps[irow], se); atomicAdd(&pzs[irow], sz); }
        }
    }
    __syncthreads();
    if (tid < TM) {
        atomicAdd(&pe[m0 + tid], ps[tid]);
        atomicAdd(&pz[m0 + tid], pzs[tid]);
    }
    __syncthreads();   // all stores/atomics complete (vmcnt drained)

    // ---- fan-in: last block to finish runs the tail ----
    if (tid == 0) {
        __threadfence();                        // release our writes
        unsigned old = atomicAdd(counter, 1u);
        tail_flag = (old == NB - 1u) ? 1 : 0;
    }
    __syncthreads();
    if (!tail_flag) return;
    __threadfence();                            // acquire others' writes

    // phase 1: log-probs for all rows (L2-hot)
    for (int i = tid; i < M_; i += 512) {
        float l = __logf(pe[i]);
        blp_g[i] = blank_z[i] - l;
        elp_g[i] = emit_z[i] - l;
    }
    __syncthreads();

    // phase 2: one wave per utterance — CE + anti-diagonal DP
    const int b = wid;                          // 8 waves = 8 utterances
    const int u = lane;
    const int base = b * T_ * U1_;
    const int sl = src_lengths[b], tl = tgt_lengths[b];

    if (u < 32) {
        int tgt = targets[b * (U1_ - 1) + u];
        float contrib = 0.0f;
        int g = base + (sl - 1) * U1_ + u;
        if (tgt != PAD_) {
            float l = __logf(pe[g]);
            float nll = l - emit_z[g];
            float smooth = (float)V_ * l - pz[g];
            const float eps_i = 0.1f / (float)(V_ - 1);
            contrib = (1.0f - 0.1f - eps_i) * nll + eps_i * smooth;
        }
#pragma unroll
        for (int off = 1; off < 32; off <<= 1) contrib += __shfl_xor(contrib, off, 64);
        if (u == 0) atomicAdd(out, contrib);
    }

    const int ua = (u < U1_) ? u : U1_ - 1;
    float val = 0.0f, afin = 0.0f;
    for (int d = 1; d <= (T_ - 1) + (U1_ - 1); d++) {
        int t = d - u;
        int tb = t - 1; tb = tb < 0 ? 0 : (tb > T_ - 1 ? T_ - 1 : tb);
        int tc = t < 0 ? 0 : (t > T_ - 1 ? T_ - 1 : t);
        float blv = blp_g[base + tb * U1_ + ua];
        float elv = elp_g[base + tc * U1_ + (ua > 0 ? ua - 1 : 0)];
        float up = __shfl_up(val, 1, 64);
        bool valid = (u < U1_) && (t >= 0) && (t < T_);
        if (valid) {
            if (t == 0) {
                val = up + elv;
            } else if (u == 0) {
                val = val + blv;
            } else {
                float a1 = val + blv;
                float a2 = up + elv;
                float mx = fmaxf(a1, a2), mn = fminf(a1, a2);
                val = mx + log1pf(__expf(mn - mx));
            }
            if (t == sl - 1 && u == tl) afin = val;
        }
    }
#pragma unroll
    for (int off = 1; off < 64; off <<= 1) afin += __shfl_xor(afin, off, 64);
    if (u == 0) {
        float bfin = blp_g[base + (sl - 1) * U1_ + tl];
        atomicAdd(out, -(afin + bfin));
    }
}

// ---------------------------------------------------------------------------
extern "C" void kernel_launch(void* const* d_in, const int* in_sizes, int n_in,
                              void* d_out, int out_size, void* d_ws, size_t ws_size,
                              hipStream_t stream)
{
    const float* x           = (const float*)d_in[0];
    const float* w           = (const float*)d_in[1];
    const float* bias        = (const float*)d_in[2];
    const int*   targets     = (const int*)d_in[3];
    const int*   src_lengths = (const int*)d_in[4];
    const int*   tgt_lengths = (const int*)d_in[5];
    float* out = (float*)d_out;

    char* p = (char*)d_ws;
    uint8_t* xf8 = (uint8_t*)p;    p += (size_t)M_ * D_;                // 17.3 MB
    uint8_t* wf8 = (uint8_t*)p;    p += (size_t)V_ * D_;                //  2.1 MB
    float* pe      = (float*)p;    p += (size_t)M_ * sizeof(float);
    float* pz      = (float*)p;    p += (size_t)M_ * sizeof(float);
    float* blank_z = (float*)p;    p += (size_t)M_ * sizeof(float);
    float* emit_z  = (float*)p;    p += (size_t)M_ * sizeof(float);
    float* blp_g   = (float*)p;    p += (size_t)M_ * sizeof(float);
    float* elp_g   = (float*)p;    p += (size_t)M_ * sizeof(float);
    unsigned* counter = (unsigned*)p;

    prep_kernel<<<2048, 256, 0, stream>>>(x, w, xf8, wf8, pe, pz, counter, out);
    gemm_fused<<<dim3(NBX, NBY), 512, 0, stream>>>(xf8, wf8, bias, targets,
                                                   src_lengths, tgt_lengths,
                                                   pe, pz, blank_z, emit_z,
                                                   blp_g, elp_g, counter, out);
}